// Round 2
// baseline (56.901 us; speedup 1.0000x reference)
//
#include <hip/hip_runtime.h>
#include <hip/hip_cooperative_groups.h>

namespace cg = cooperative_groups;

#define NLOC 100
#define TPB 512      // 8 waves per block
#define PXW 32       // pixels per lane; chunk = 64*PXW
#define CHUNK 2048

// ws layout: pm [B*NLOC*nsub floats] | wts [B*NLOC floats] | nc [B ints]
// pm[(b*NLOC+n)*nsub + sub] = partial min d^2 for true-loc (b,n) over block chunk `sub`.
// Every slot is written unconditionally every call -> no init/memset needed.

__global__ __launch_bounds__(TPB, 2)
void fused_kernel(const float* __restrict__ loc, const float* __restrict__ unc,
                  const float* __restrict__ tloc, const float* __restrict__ prob,
                  float* __restrict__ pm, float* __restrict__ wts,
                  int* __restrict__ nc, float* __restrict__ out,
                  int P, int B, int nsub)
{
    __shared__ float2 s_t[NLOC];
    __shared__ float s_d[8 * NLOC];   // phase 2 only (B<=8 for this problem)
    __shared__ float s_val[32];

    const int tid  = (int)threadIdx.x;
    const int wv   = tid >> 6;
    const int lane = tid & 63;
    const int bid  = (int)blockIdx.x;
    const int b    = bid / nsub;
    const int sub  = bid % nsub;

    // stage this batch's true locations (broadcast reads later)
    for (int i = tid; i < NLOC; i += TPB)
        s_t[i] = reinterpret_cast<const float2*>(tloc)[b * NLOC + i];
    __syncthreads();

    const int base = sub * CHUNK;
    const float2* locp  = reinterpret_cast<const float2*>(loc) + (size_t)b * P;
    const float*  probp = prob + (size_t)b * P;

    // ---- phase 1a: whole chunk in registers, sentinel for non-confident ----
    float px[PXW], py[PXW], a2[PXW];
    #pragma unroll
    for (int j = 0; j < PXW; ++j) {
        int p = base + j * 64 + lane;
        bool inb = p < P;
        float pv  = inb ? probp[p] : 0.0f;
        float2 xy = inb ? locp[p] : make_float2(0.f, 0.f);
        bool conf = pv > 0.5f;
        px[j] = conf ? xy.x : 1.0e15f;     // sentinel: d^2 ~ 2e30, beats nothing real
        py[j] = conf ? xy.y : 1.0e15f;
        a2[j] = __builtin_fmaf(px[j], px[j], py[j] * py[j]);
    }

    // each wave owns locs n == wv (mod 8); covers ALL chunk pixels (3-op inner)
    for (int n = wv; n < NLOC; n += 8) {
        float bx = s_t[n].x, by = s_t[n].y;
        float m2bx = -2.0f * bx, m2by = -2.0f * by;
        float b2 = __builtin_fmaf(bx, bx, by * by);
        float m = 3.0e38f;
        #pragma unroll
        for (int j = 0; j < PXW; ++j) {
            float t = __builtin_fmaf(px[j], m2bx, a2[j]);   // a^2 - 2bx*x
            t = __builtin_fmaf(py[j], m2by, t);             // ... - 2by*y  (= d^2 - b^2)
            m = fminf(m, t);
        }
        #pragma unroll
        for (int off = 32; off; off >>= 1)
            m = fminf(m, __shfl_xor(m, off));
        if (lane == 0)
            pm[((size_t)b * NLOC + n) * nsub + sub] = fmaxf(m + b2, 0.0f);
    }

    // ---- phase 1b: ordered scan for first-NLOC weights (wave 0 of sub==0) ----
    if (sub == 0 && wv == 0) {
        const float* up = unc + (size_t)b * P;
        const int nchunks = (P + 63) >> 6;
        int nconf = 0;
        for (int c = 0; c < nchunks; ++c) {
            if (nconf >= NLOC) break;
            int p = (c << 6) + lane;
            bool inb = p < P;
            float pv = probp[inb ? p : 0];
            bool conf = inb && (pv > 0.5f);
            unsigned long long mask = __ballot(conf);
            int pref = __popcll(mask & ((1ull << lane) - 1ull));
            int r = nconf + pref;
            if (conf && r < NLOC) wts[b * NLOC + r] = expf(-up[p]);
            nconf += __popcll(mask);
        }
        if (nconf < NLOC) {   // torch quirk: ranks continue into non-confident pixels
            int nnon = 0;
            for (int c = 0; c < nchunks; ++c) {
                if (nconf + nnon >= NLOC) break;
                int p = (c << 6) + lane;
                bool inb = p < P;
                float pv = probp[inb ? p : 0];
                bool nonc = inb && !(pv > 0.5f);
                unsigned long long mask = __ballot(nonc);
                int pref = __popcll(mask & ((1ull << lane) - 1ull));
                int r = nconf + nnon + pref;
                if (nonc && r < NLOC) wts[b * NLOC + r] = expf(-up[p]);
                nnon += __popcll(mask);
            }
        }
        if (lane == 0) nc[b] = (nconf > 0) ? 1 : 0;
    }

    cg::this_grid().sync();

    // ---- phase 2: block 0 reduces partials and finishes ----
    if (bid != 0) return;

    const int npairs = B * NLOC;
    for (int idx = tid; idx < npairs; idx += TPB) {
        const float4* pp = reinterpret_cast<const float4*>(pm + (size_t)idx * nsub);
        float m = 3.0e38f;
        for (int k = 0; k < nsub / 4; ++k) {
            float4 v = pp[k];
            m = fminf(m, fminf(fminf(v.x, v.y), fminf(v.z, v.w)));
        }
        s_d[idx] = sqrtf(m);
    }
    __syncthreads();

    for (int bb = wv; bb < B; bb += 8) {
        float sum = 0.0f;
        int vbase = 0;
        for (int c = 0; c < (NLOC + 63) / 64; ++c) {
            int j = c * 64 + lane;
            bool valid = false;
            if (j < NLOC) {
                float2 t = reinterpret_cast<const float2*>(tloc)[bb * NLOC + j];
                valid = (t.x >= 0.f) && (t.y >= 0.f);
            }
            unsigned long long mask = __ballot(valid);
            int rank = vbase + __popcll(mask & ((1ull << lane) - 1ull));
            if (valid) sum += s_d[bb * NLOC + j] * wts[bb * NLOC + rank];
            vbase += __popcll(mask);
        }
        #pragma unroll
        for (int off = 32; off; off >>= 1)
            sum += __shfl_xor(sum, off);
        if (lane == 0) {
            int nv = vbase;
            s_val[bb] = (nv == 0) ? 0.0f
                       : ((nc[bb] == 0) ? 10.0f : sum / (float)nv);
        }
    }
    __syncthreads();
    if (tid == 0) {
        float v = 0.0f;
        for (int i = 0; i < B; ++i) v += s_val[i];
        out[0] = v / (float)B;
    }
}

extern "C" void kernel_launch(void* const* d_in, const int* in_sizes, int n_in,
                              void* d_out, int out_size, void* d_ws, size_t ws_size,
                              hipStream_t stream)
{
    const float* loc  = (const float*)d_in[0];   // [B,H,W,2]
    const float* unc  = (const float*)d_in[1];   // [B,H,W,1]
    const float* tloc = (const float*)d_in[2];   // [B,N,2]
    const float* prob = (const float*)d_in[3];   // [B,1,H,W]
    float* out = (float*)d_out;

    int B = in_sizes[2] / (2 * NLOC);
    int P = in_sizes[1] / B;
    int nsub = (P + CHUNK - 1) / CHUNK;          // 32 for P=65536

    float* pm  = (float*)d_ws;
    float* wts = pm + (size_t)B * NLOC * nsub;
    int*   ncp = (int*)(wts + (size_t)B * NLOC);

    void* args[] = {(void*)&loc, (void*)&unc, (void*)&tloc, (void*)&prob,
                    (void*)&pm, (void*)&wts, (void*)&ncp, (void*)&out,
                    (void*)&P, (void*)&B, (void*)&nsub};
    hipLaunchCooperativeKernel((void*)fused_kernel, dim3(B * nsub), dim3(TPB),
                               args, 0, stream);
}

// Round 3
// 23.541 us; speedup vs baseline: 2.4171x; 2.4171x over previous
//
#include <hip/hip_runtime.h>

#define NLOC 100
#define TPB 512          // 8 waves
#define NWAVE 8
#define NLW 13           // ceil(NLOC / NWAVE)
#define CHUNK 2048       // pixels per block
#define TILE 16          // pixels per lane per register tile (2 tiles = 32 px/lane)

// ws layout: pm [B*NLOC*nsub floats] | wts [B*NLOC floats] | nc [B ints]
// Every pm slot is written unconditionally every call -> no init needed.

__global__ __launch_bounds__(TPB, 2)
void k_partial(const float* __restrict__ loc, const float* __restrict__ unc,
               const float* __restrict__ prob, const float* __restrict__ tloc,
               float* __restrict__ pm, float* __restrict__ wts,
               int* __restrict__ nc, int P, int nsub)
{
    __shared__ float2 s_t[NLW * NWAVE];   // padded to 104

    const int tid  = (int)threadIdx.x;
    const int wv   = tid >> 6;
    const int lane = tid & 63;
    const int sub  = (int)blockIdx.x;
    const int b    = (int)blockIdx.y;

    for (int i = tid; i < NLW * NWAVE; i += TPB)
        s_t[i] = (i < NLOC) ? reinterpret_cast<const float2*>(tloc)[b * NLOC + i]
                            : make_float2(0.f, 0.f);
    __syncthreads();

    // per-wave loc constants in registers (26 regs)
    float bxr[NLW], byr[NLW], m[NLW];
    #pragma unroll
    for (int i = 0; i < NLW; ++i) {
        float2 t = s_t[wv + i * NWAVE];
        bxr[i] = t.x; byr[i] = t.y;
        m[i] = 3.0e38f;
    }

    const int base = sub * CHUNK;
    const float2* locp  = reinterpret_cast<const float2*>(loc) + (size_t)b * P;
    const float*  probp = prob + (size_t)b * P;

    // two register tiles of 16 pixels/lane; sentinel for non-confident pixels
    #pragma unroll
    for (int t = 0; t < CHUNK / (TILE * 64); ++t) {
        float px[TILE], py[TILE], pa2[TILE];
        #pragma unroll
        for (int j = 0; j < TILE; ++j) {
            int p = base + t * (TILE * 64) + j * 64 + lane;
            bool inb = p < P;
            float pv  = inb ? probp[p] : 0.0f;
            float2 xy = inb ? locp[p] : make_float2(0.f, 0.f);
            bool conf = pv > 0.5f;
            px[j] = conf ? xy.x : 1.0e15f;    // sentinel: contributes ~2e30, beats nothing
            py[j] = conf ? xy.y : 1.0e15f;
            pa2[j] = __builtin_fmaf(px[j], px[j], py[j] * py[j]);
        }
        #pragma unroll
        for (int i = 0; i < NLW; ++i) {
            float nbx = bxr[i] * -2.0f, nby = byr[i] * -2.0f;
            float mm = m[i];
            #pragma unroll
            for (int j = 0; j < TILE; ++j) {
                float d = __builtin_fmaf(px[j], nbx, pa2[j]);   // |a|^2 - 2bx*ax
                d = __builtin_fmaf(py[j], nby, d);              //        - 2by*ay
                mm = fminf(mm, d);
            }
            m[i] = mm;
        }
    }

    #pragma unroll
    for (int i = 0; i < NLW; ++i) {
        float mm = m[i];
        #pragma unroll
        for (int off = 32; off; off >>= 1)
            mm = fminf(mm, __shfl_xor(mm, off));
        int n = wv + i * NWAVE;
        if (lane == 0 && n < NLOC) {
            float b2 = __builtin_fmaf(bxr[i], bxr[i], byr[i] * byr[i]);
            pm[((size_t)b * NLOC + n) * nsub + sub] = fmaxf(mm + b2, 0.0f);  // min d^2
        }
    }

    // ordered scan for first-NLOC weights: wave 0 of sub==0 block per batch
    if (sub == 0 && wv == 0) {
        const float* up = unc + (size_t)b * P;
        const int nchunks = (P + 63) >> 6;
        int nconf = 0;
        for (int c = 0; c < nchunks; ++c) {
            if (nconf >= NLOC) break;
            int p = (c << 6) + lane;
            bool inb = p < P;
            float pv = probp[inb ? p : 0];
            bool conf = inb && (pv > 0.5f);
            unsigned long long mask = __ballot(conf);
            int pref = __popcll(mask & ((1ull << lane) - 1ull));
            int r = nconf + pref;
            if (conf && r < NLOC) wts[b * NLOC + r] = expf(-up[p]);
            nconf += __popcll(mask);
        }
        if (nconf < NLOC) {   // torch quirk: ranks continue into non-confident pixels
            int nnon = 0;
            for (int c = 0; c < nchunks; ++c) {
                if (nconf + nnon >= NLOC) break;
                int p = (c << 6) + lane;
                bool inb = p < P;
                float pv = probp[inb ? p : 0];
                bool nonc = inb && !(pv > 0.5f);
                unsigned long long mask = __ballot(nonc);
                int pref = __popcll(mask & ((1ull << lane) - 1ull));
                int r = nconf + nnon + pref;
                if (nonc && r < NLOC) wts[b * NLOC + r] = expf(-up[p]);
                nnon += __popcll(mask);
            }
        }
        if (lane == 0) nc[b] = (nconf > 0) ? 1 : 0;
    }
}

__global__ __launch_bounds__(1024)
void k_final(const float* __restrict__ tloc, const float* __restrict__ pm,
             const float* __restrict__ wts, const int* __restrict__ nc,
             float* __restrict__ out, int B, int nsub)
{
    __shared__ float s_d[8 * NLOC];
    __shared__ float s_val[32];
    const int tid  = (int)threadIdx.x;
    const int wv   = tid >> 6;
    const int lane = tid & 63;

    const int npairs = B * NLOC;
    for (int idx = tid; idx < npairs; idx += 1024) {
        const float4* pp = reinterpret_cast<const float4*>(pm + (size_t)idx * nsub);
        float mv = 3.0e38f;
        for (int k = 0; k < nsub / 4; ++k) {     // independent loads, latency-overlapped
            float4 v = pp[k];
            mv = fminf(mv, fminf(fminf(v.x, v.y), fminf(v.z, v.w)));
        }
        s_d[idx] = sqrtf(mv);
    }
    __syncthreads();

    for (int bb = wv; bb < B; bb += 16) {
        float sum = 0.0f;
        int vbase = 0;
        for (int c = 0; c < (NLOC + 63) / 64; ++c) {
            int j = c * 64 + lane;
            bool valid = false;
            if (j < NLOC) {
                float2 t = reinterpret_cast<const float2*>(tloc)[bb * NLOC + j];
                valid = (t.x >= 0.f) && (t.y >= 0.f);
            }
            unsigned long long mask = __ballot(valid);
            int rank = vbase + __popcll(mask & ((1ull << lane) - 1ull));
            if (valid) sum += s_d[bb * NLOC + j] * wts[bb * NLOC + rank];
            vbase += __popcll(mask);
        }
        #pragma unroll
        for (int off = 32; off; off >>= 1)
            sum += __shfl_xor(sum, off);
        if (lane == 0)
            s_val[bb] = (vbase == 0) ? 0.0f
                        : ((nc[bb] == 0) ? 10.0f : sum / (float)vbase);
    }
    __syncthreads();
    if (tid == 0) {
        float v = 0.0f;
        for (int i = 0; i < B; ++i) v += s_val[i];
        out[0] = v / (float)B;
    }
}

extern "C" void kernel_launch(void* const* d_in, const int* in_sizes, int n_in,
                              void* d_out, int out_size, void* d_ws, size_t ws_size,
                              hipStream_t stream)
{
    const float* loc  = (const float*)d_in[0];   // [B,H,W,2]
    const float* unc  = (const float*)d_in[1];   // [B,H,W,1]
    const float* tloc = (const float*)d_in[2];   // [B,N,2]
    const float* prob = (const float*)d_in[3];   // [B,1,H,W]
    float* out = (float*)d_out;

    int B = in_sizes[2] / (2 * NLOC);
    int P = in_sizes[1] / B;
    int nsub = (P + CHUNK - 1) / CHUNK;          // 32 for P=65536

    float* pm  = (float*)d_ws;
    float* wts = pm + (size_t)B * NLOC * nsub;
    int*   ncp = (int*)(wts + (size_t)B * NLOC);

    hipLaunchKernelGGL(k_partial, dim3(nsub, B), dim3(TPB), 0, stream,
                       loc, unc, prob, tloc, pm, wts, ncp, P, nsub);
    hipLaunchKernelGGL(k_final, dim3(1), dim3(1024), 0, stream,
                       tloc, pm, wts, ncp, out, B, nsub);
}